// Round 1
// baseline (267.254 us; speedup 1.0000x reference)
//
#include <hip/hip_runtime.h>
#include <stdint.h>

#define NB 32
#define NL 1024
#define ND 256
// attn fp32 row = 1024 f32 = 4096 B = 2048 u16 slots. Pack bf16 P in slots
// [0,1024); per-row partial sums (8 n-blocks) live in f32 slots [512,520).
#define ROWU16 2048

typedef __attribute__((ext_vector_type(8))) __bf16 bf16x8;
typedef __attribute__((ext_vector_type(8))) uint16_t u16x8;
typedef __attribute__((ext_vector_type(4))) float f32x4;

__device__ __forceinline__ uint16_t f2bf(float f) {
  union { float f; uint32_t u; } v; v.f = f;
  return (uint16_t)((v.u + 0x7fffu + ((v.u >> 16) & 1u)) >> 16);
}
__device__ __forceinline__ float bf2f(uint16_t h) {
  union { uint32_t u; float f; } v; v.u = ((uint32_t)h) << 16;
  return v.f;
}

#define GLD_LDS16(g, l)                                                        \
  __builtin_amdgcn_global_load_lds(                                            \
      (__attribute__((address_space(1))) void*)(g),                            \
      (__attribute__((address_space(3))) void*)(l), 16, 0, 0)

// ---------------------------------------------------------------------------
// Kernel 0: q fp32 -> Qb bf16 [b][l][d]  and  Qt bf16 [b][d][l]
// ---------------------------------------------------------------------------
__global__ __launch_bounds__(256) void convert_kernel(
    const float* __restrict__ q, uint16_t* __restrict__ qb,
    uint16_t* __restrict__ qt) {
  __shared__ uint16_t tile[64][72];
  int b = blockIdx.z;
  int l0 = blockIdx.x * 64, d0 = blockIdx.y * 64;
  int t = threadIdx.x;
  int r = t >> 4;
  int c4 = (t & 15) * 4;
  const float* qsrc = q + (size_t)b * NL * ND;
  uint16_t* qbb = qb + (size_t)b * NL * ND;
  uint16_t* qtb = qt + (size_t)b * ND * NL;
#pragma unroll
  for (int i = 0; i < 4; i++) {
    int row = r + 16 * i;
    float4 v = *(const float4*)(qsrc + (size_t)(l0 + row) * ND + d0 + c4);
    ushort4 h;
    h.x = f2bf(v.x); h.y = f2bf(v.y); h.z = f2bf(v.z); h.w = f2bf(v.w);
    *(ushort4*)(qbb + (size_t)(l0 + row) * ND + d0 + c4) = h;
    tile[row][c4 + 0] = h.x; tile[row][c4 + 1] = h.y;
    tile[row][c4 + 2] = h.z; tile[row][c4 + 3] = h.w;
  }
  __syncthreads();
#pragma unroll
  for (int i = 0; i < 4; i++) {
    int drow = r + 16 * i;
    ushort4 h;
    h.x = tile[c4 + 0][drow]; h.y = tile[c4 + 1][drow];
    h.z = tile[c4 + 2][drow]; h.w = tile[c4 + 3][drow];
    *(ushort4*)(qtb + (size_t)(d0 + drow) * NL + l0 + c4) = h;
  }
}

// ---------------------------------------------------------------------------
// Kernel 1: e = exp(S/16) (s==0 -> 0), S = Qb Qb^T. Writes bf16 e packed into
// attn rows + per-(row, n-block) fp32 partial sums into spare slots.
// ---------------------------------------------------------------------------
__global__ __launch_bounds__(256) void qk_kernel(
    const uint16_t* __restrict__ qb, float* __restrict__ attn_f32) {
  __shared__ alignas(16) uint16_t As[128 * 32];
  __shared__ alignas(16) uint16_t Bs[128 * 32];
  __shared__ float rp[128][2];
  int b = blockIdx.z;
  int m0 = blockIdx.x * 128, n0 = blockIdx.y * 128;
  const uint16_t* Q = qb + (size_t)b * NL * ND;
  int tid = threadIdx.x, lane = tid & 63, wave = tid >> 6;
  int wm = (wave & 1) * 64, wn = (wave >> 1) * 64;
  int quad = lane >> 4, l15 = lane & 15;
  f32x4 acc[4][4] = {};

  for (int k0 = 0; k0 < ND; k0 += 32) {
    __syncthreads();
#pragma unroll
    for (int i = 0; i < 2; i++) {
      int c = i * 256 + wave * 64 + lane;
      int row = c >> 2, cc = c & 3;
      int sw = (row >> 1) & 3;
      int gc = k0 + ((cc ^ sw) * 8);
      GLD_LDS16(Q + (size_t)(m0 + row) * ND + gc,
                As + (size_t)(i * 256 + wave * 64) * 8);
      GLD_LDS16(Q + (size_t)(n0 + row) * ND + gc,
                Bs + (size_t)(i * 256 + wave * 64) * 8);
    }
    __syncthreads();
    bf16x8 af[4], bfr[4];
#pragma unroll
    for (int t = 0; t < 4; t++) {
      int ra = wm + t * 16 + l15;
      af[t] = *(const bf16x8*)(As + ra * 32 + ((quad ^ ((ra >> 1) & 3)) * 8));
      int rb = wn + t * 16 + l15;
      bfr[t] = *(const bf16x8*)(Bs + rb * 32 + ((quad ^ ((rb >> 1) & 3)) * 8));
    }
#pragma unroll
    for (int tm = 0; tm < 4; tm++)
#pragma unroll
      for (int tn = 0; tn < 4; tn++)
        acc[tm][tn] = __builtin_amdgcn_mfma_f32_16x16x32_bf16(
            af[tm], bfr[tn], acc[tm][tn], 0, 0, 0);
  }

  const float kf = 0.09016844005555f;  // log2(e)/16
  uint16_t* attn_u16 = (uint16_t*)attn_f32;
  size_t gbase = (size_t)b * NL;
#pragma unroll
  for (int tm = 0; tm < 4; tm++) {
    int rbl = wm + tm * 16 + quad * 4;  // local row base (j adds 0..3)
    float rsum[4] = {0.f, 0.f, 0.f, 0.f};
#pragma unroll
    for (int tn = 0; tn < 4; tn++) {
      int col = n0 + wn + tn * 16 + l15;
#pragma unroll
      for (int j = 0; j < 4; j++) {
        float s = acc[tm][tn][j];
        float e = (s == 0.0f) ? 0.0f : __builtin_amdgcn_exp2f(s * kf);
        attn_u16[(gbase + m0 + rbl + j) * ROWU16 + col] = f2bf(e);
        rsum[j] += e;
      }
    }
#pragma unroll
    for (int j = 0; j < 4; j++) {
      float v = rsum[j];
      v += __shfl_xor(v, 1, 64);
      v += __shfl_xor(v, 2, 64);
      v += __shfl_xor(v, 4, 64);
      v += __shfl_xor(v, 8, 64);
      if (l15 == 0) rp[rbl + j][wave >> 1] = v;
    }
  }
  __syncthreads();
  if (tid < 128) {
    float s = rp[tid][0] + rp[tid][1];
    attn_f32[(gbase + m0 + tid) * (size_t)NL + 512 + blockIdx.y] = s;
  }
}

// ---------------------------------------------------------------------------
// Kernel 2 (fused): out = (P @ Q) * inv_rowsum AND in-place expansion of the
// packed bf16 P rows into normalized fp32 attn rows.
//
// Block = 512 threads (8 waves), tile 128 (m) x 256 (full D). Grid (8,1,NB):
// each block is the EXCLUSIVE reader/writer of its 128 attn rows, so the
// in-place expand has no cross-block hazard.
//
// K runs HIGH -> LOW: expansion of chunk k0 writes f32 bytes [4*k0, 4*k0+128)
// of a row while all remaining packed reads live at bytes < 2*k0 (+64 for the
// current chunk, which is already drained into LDS by the barrier). So the
// streaming in-place expand never clobbers unread packed data.
// ---------------------------------------------------------------------------
__global__ __launch_bounds__(512) void pv_kernel(
    float* __restrict__ attn_f32, const uint16_t* __restrict__ qt,
    float* __restrict__ out) {
  __shared__ alignas(16) uint16_t As[128 * 32];
  __shared__ alignas(16) uint16_t Bs[256 * 32];
  __shared__ float inv_lds[128];
  int b = blockIdx.z;
  int m0 = blockIdx.x * 128;
  const uint16_t* Ap = (const uint16_t*)attn_f32 + (size_t)b * NL * ROWU16;
  const uint16_t* Bt = qt + (size_t)b * ND * NL;
  int tid = threadIdx.x, lane = tid & 63, wave = tid >> 6;
  int wm = (wave & 1) * 64, wn = (wave >> 1) * 64;  // wn in {0,64,128,192}
  int quad = lane >> 4, l15 = lane & 15;
  f32x4 acc[4][4] = {};

  if (tid < 128) {
    const float* pf = attn_f32 + (size_t)(b * NL + m0 + tid) * NL + 512;
    float s = pf[0] + pf[1] + pf[2] + pf[3] + pf[4] + pf[5] + pf[6] + pf[7];
    inv_lds[tid] = (s > 0.0f) ? 1.0f / s : 0.0f;
  }

  // expansion assignment: 512 threads cover 128 rows x 4 chunks-of-8
  int xr = tid >> 2;             // local row 0..127
  int xc = tid & 3;              // which 8-u16 chunk within the 32-u16 K-step
  int xsw = (xr >> 1) & 3;
  float* xdst_row = attn_f32 + (size_t)(b * NL + m0 + xr) * NL + xc * 8;

  for (int k0 = NL - 32; k0 >= 0; k0 -= 32) {
    __syncthreads();
    {
      // A: 128 rows x 32 u16, one gld_lds across 512 threads
      int c = tid;
      int row = c >> 2, cc = c & 3;
      int sw = (row >> 1) & 3;
      int gc = k0 + ((cc ^ sw) * 8);
      GLD_LDS16(Ap + (size_t)(m0 + row) * ROWU16 + gc,
                As + (size_t)(wave * 64) * 8);
    }
#pragma unroll
    for (int i = 0; i < 2; i++) {
      // B: 256 rows x 32 u16, two gld_lds across 512 threads
      int c = i * 512 + tid;
      int row = c >> 2, cc = c & 3;
      int sw = (row >> 1) & 3;
      int gc = k0 + ((cc ^ sw) * 8);
      GLD_LDS16(Bt + (size_t)row * NL + gc,
                Bs + (size_t)(i * 512 + wave * 64) * 8);
    }
    __syncthreads();
    bf16x8 af[4], bfr[4];
#pragma unroll
    for (int t = 0; t < 4; t++) {
      int ra = wm + t * 16 + l15;
      af[t] = *(const bf16x8*)(As + ra * 32 + ((quad ^ ((ra >> 1) & 3)) * 8));
      int rb = wn + t * 16 + l15;
      bfr[t] = *(const bf16x8*)(Bs + rb * 32 + ((quad ^ ((rb >> 1) & 3)) * 8));
    }
#pragma unroll
    for (int tm = 0; tm < 4; tm++)
#pragma unroll
      for (int tn = 0; tn < 4; tn++)
        acc[tm][tn] = __builtin_amdgcn_mfma_f32_16x16x32_bf16(
            af[tm], bfr[tn], acc[tm][tn], 0, 0, 0);

    // In-loop expansion of this K-chunk from LDS -> normalized f32 attn.
    // Reads As (valid until next top-of-loop barrier); writes global bytes
    // [4*k0, 4*k0+128) of the row, which no future (lower-k0) read touches.
    {
      u16x8 hv = *(const u16x8*)(As + xr * 32 + ((xc ^ xsw) * 8));
      float inv = inv_lds[xr];
      float4 lo, hi;
      lo.x = bf2f(hv[0]) * inv;
      lo.y = bf2f(hv[1]) * inv;
      lo.z = bf2f(hv[2]) * inv;
      lo.w = bf2f(hv[3]) * inv;
      hi.x = bf2f(hv[4]) * inv;
      hi.y = bf2f(hv[5]) * inv;
      hi.z = bf2f(hv[6]) * inv;
      hi.w = bf2f(hv[7]) * inv;
      float4* dp = (float4*)(xdst_row + k0);
      dp[0] = lo;
      dp[1] = hi;
    }
  }

  float* O = out + (size_t)b * NL * ND;
#pragma unroll
  for (int tm = 0; tm < 4; tm++) {
    int rbl = wm + tm * 16 + quad * 4;
#pragma unroll
    for (int tn = 0; tn < 4; tn++) {
      int col = wn + tn * 16 + l15;
#pragma unroll
      for (int j = 0; j < 4; j++)
        O[(size_t)(m0 + rbl + j) * ND + col] = acc[tm][tn][j] * inv_lds[rbl + j];
    }
  }
}

// ---------------------------------------------------------------------------
extern "C" void kernel_launch(void* const* d_in, const int* in_sizes, int n_in,
                              void* d_out, int out_size, void* d_ws,
                              size_t ws_size, hipStream_t stream) {
  (void)in_sizes; (void)n_in; (void)out_size; (void)ws_size;
  const float* q = (const float*)d_in[0];
  float* out = (float*)d_out;
  float* attn = out + (size_t)NB * NL * ND;  // [output | attn] concat
  uint16_t* qb = (uint16_t*)d_ws;            // 16 MiB
  uint16_t* qt = qb + (size_t)NB * NL * ND;  // 16 MiB  (total = 32 MiB, as before)

  convert_kernel<<<dim3(16, 4, NB), 256, 0, stream>>>(q, qb, qt);
  qk_kernel<<<dim3(8, 8, NB), 256, 0, stream>>>(qb, attn);
  pv_kernel<<<dim3(8, 1, NB), 512, 0, stream>>>(attn, qt, out);
}

// Round 2
// 266.440 us; speedup vs baseline: 1.0031x; 1.0031x over previous
//
#include <hip/hip_runtime.h>
#include <stdint.h>

#define NB 32
#define NL 1024
#define ND 256
// attn fp32 row = 1024 f32 = 4096 B = 2048 u16 slots. Pack bf16 P in slots
// [0,1024); per-row partial sums (8 n-blocks) live in f32 slots [512,520).
#define ROWU16 2048

typedef __attribute__((ext_vector_type(8))) __bf16 bf16x8;
typedef __attribute__((ext_vector_type(8))) uint16_t u16x8;
typedef __attribute__((ext_vector_type(4))) float f32x4;

__device__ __forceinline__ uint16_t f2bf(float f) {
  union { float f; uint32_t u; } v; v.f = f;
  return (uint16_t)((v.u + 0x7fffu + ((v.u >> 16) & 1u)) >> 16);
}
__device__ __forceinline__ float bf2f(uint16_t h) {
  union { uint32_t u; float f; } v; v.u = ((uint32_t)h) << 16;
  return v.f;
}

#define GLD_LDS16(g, l)                                                        \
  __builtin_amdgcn_global_load_lds(                                            \
      (__attribute__((address_space(1))) void*)(g),                            \
      (__attribute__((address_space(3))) void*)(l), 16, 0, 0)

// ---------------------------------------------------------------------------
// Kernel 0: q fp32 -> Qb bf16 [b][l][d]  and  Qt bf16 [b][d][l]
// ---------------------------------------------------------------------------
__global__ __launch_bounds__(256) void convert_kernel(
    const float* __restrict__ q, uint16_t* __restrict__ qb,
    uint16_t* __restrict__ qt) {
  __shared__ uint16_t tile[64][72];
  int b = blockIdx.z;
  int l0 = blockIdx.x * 64, d0 = blockIdx.y * 64;
  int t = threadIdx.x;
  int r = t >> 4;
  int c4 = (t & 15) * 4;
  const float* qsrc = q + (size_t)b * NL * ND;
  uint16_t* qbb = qb + (size_t)b * NL * ND;
  uint16_t* qtb = qt + (size_t)b * ND * NL;
#pragma unroll
  for (int i = 0; i < 4; i++) {
    int row = r + 16 * i;
    float4 v = *(const float4*)(qsrc + (size_t)(l0 + row) * ND + d0 + c4);
    ushort4 h;
    h.x = f2bf(v.x); h.y = f2bf(v.y); h.z = f2bf(v.z); h.w = f2bf(v.w);
    *(ushort4*)(qbb + (size_t)(l0 + row) * ND + d0 + c4) = h;
    tile[row][c4 + 0] = h.x; tile[row][c4 + 1] = h.y;
    tile[row][c4 + 2] = h.z; tile[row][c4 + 3] = h.w;
  }
  __syncthreads();
#pragma unroll
  for (int i = 0; i < 4; i++) {
    int drow = r + 16 * i;
    ushort4 h;
    h.x = tile[c4 + 0][drow]; h.y = tile[c4 + 1][drow];
    h.z = tile[c4 + 2][drow]; h.w = tile[c4 + 3][drow];
    *(ushort4*)(qtb + (size_t)(d0 + drow) * NL + l0 + c4) = h;
  }
}

// ---------------------------------------------------------------------------
// Kernel 1: e = exp(S/16) (s==0 -> 0), S = Qb Qb^T. Writes bf16 e packed into
// attn rows + per-(row, n-block) fp32 partial sums into spare slots.
// ---------------------------------------------------------------------------
__global__ __launch_bounds__(256) void qk_kernel(
    const uint16_t* __restrict__ qb, float* __restrict__ attn_f32) {
  __shared__ alignas(16) uint16_t As[128 * 32];
  __shared__ alignas(16) uint16_t Bs[128 * 32];
  __shared__ float rp[128][2];
  int b = blockIdx.z;
  int m0 = blockIdx.x * 128, n0 = blockIdx.y * 128;
  const uint16_t* Q = qb + (size_t)b * NL * ND;
  int tid = threadIdx.x, lane = tid & 63, wave = tid >> 6;
  int wm = (wave & 1) * 64, wn = (wave >> 1) * 64;
  int quad = lane >> 4, l15 = lane & 15;
  f32x4 acc[4][4] = {};

  for (int k0 = 0; k0 < ND; k0 += 32) {
    __syncthreads();
#pragma unroll
    for (int i = 0; i < 2; i++) {
      int c = i * 256 + wave * 64 + lane;
      int row = c >> 2, cc = c & 3;
      int sw = (row >> 1) & 3;
      int gc = k0 + ((cc ^ sw) * 8);
      GLD_LDS16(Q + (size_t)(m0 + row) * ND + gc,
                As + (size_t)(i * 256 + wave * 64) * 8);
      GLD_LDS16(Q + (size_t)(n0 + row) * ND + gc,
                Bs + (size_t)(i * 256 + wave * 64) * 8);
    }
    __syncthreads();
    bf16x8 af[4], bfr[4];
#pragma unroll
    for (int t = 0; t < 4; t++) {
      int ra = wm + t * 16 + l15;
      af[t] = *(const bf16x8*)(As + ra * 32 + ((quad ^ ((ra >> 1) & 3)) * 8));
      int rb = wn + t * 16 + l15;
      bfr[t] = *(const bf16x8*)(Bs + rb * 32 + ((quad ^ ((rb >> 1) & 3)) * 8));
    }
#pragma unroll
    for (int tm = 0; tm < 4; tm++)
#pragma unroll
      for (int tn = 0; tn < 4; tn++)
        acc[tm][tn] = __builtin_amdgcn_mfma_f32_16x16x32_bf16(
            af[tm], bfr[tn], acc[tm][tn], 0, 0, 0);
  }

  const float kf = 0.09016844005555f;  // log2(e)/16
  uint16_t* attn_u16 = (uint16_t*)attn_f32;
  size_t gbase = (size_t)b * NL;
#pragma unroll
  for (int tm = 0; tm < 4; tm++) {
    int rbl = wm + tm * 16 + quad * 4;  // local row base (j adds 0..3)
    float rsum[4] = {0.f, 0.f, 0.f, 0.f};
#pragma unroll
    for (int tn = 0; tn < 4; tn++) {
      int col = n0 + wn + tn * 16 + l15;
#pragma unroll
      for (int j = 0; j < 4; j++) {
        float s = acc[tm][tn][j];
        float e = (s == 0.0f) ? 0.0f : __builtin_amdgcn_exp2f(s * kf);
        union { __bf16 b; uint16_t u; } cv;
        cv.b = (__bf16)e;  // native cvt (v_cvt_pk_bf16_f32), RNE same as f2bf
        attn_u16[(gbase + m0 + rbl + j) * ROWU16 + col] = cv.u;
        rsum[j] += e;
      }
    }
#pragma unroll
    for (int j = 0; j < 4; j++) {
      float v = rsum[j];
      v += __shfl_xor(v, 1, 64);
      v += __shfl_xor(v, 2, 64);
      v += __shfl_xor(v, 4, 64);
      v += __shfl_xor(v, 8, 64);
      if (l15 == 0) rp[rbl + j][wave >> 1] = v;
    }
  }
  __syncthreads();
  if (tid < 128) {
    float s = rp[tid][0] + rp[tid][1];
    attn_f32[(gbase + m0 + tid) * (size_t)NL + 512 + blockIdx.y] = s;
  }
}

// ---------------------------------------------------------------------------
// Kernel 2 (fused): out = (P @ Q) * inv_rowsum AND in-place expansion of the
// packed bf16 P rows into normalized fp32 attn rows.
//
// Tile 64 (m) x 256 (full D), 256 threads (4 waves, wn = wave*64).
// Grid (16,1,NB) = 512 blocks -> 2 blocks/CU co-resident: two independent
// barrier groups per CU overlap each other's gld_lds/store drains (m114).
// Each block is the EXCLUSIVE reader/writer of its 64 attn rows.
//
// K runs HIGH -> LOW. Expansion of chunk k0 is COMPUTED in iteration k0 (from
// LDS, registers) but STORED one iteration later, right beside the gld_lds
// issue, so the store drain overlaps the load drain at the same barrier
// instead of serializing before it. Safety: the deferred store for chunk
// k0+32 writes f32 bytes [4*k0+128, 4*k0+256) of a row; iteration k0's packed
// reads live at bytes [2*k0, 2*k0+64) — disjoint for all k0 >= 0.
// ---------------------------------------------------------------------------
__global__ __launch_bounds__(256) void pv_kernel(
    float* __restrict__ attn_f32, const uint16_t* __restrict__ qt,
    float* __restrict__ out) {
  __shared__ alignas(16) uint16_t As[64 * 32];
  __shared__ alignas(16) uint16_t Bs[256 * 32];
  __shared__ float inv_lds[64];
  int b = blockIdx.z;
  int m0 = blockIdx.x * 64;
  const uint16_t* Ap = (const uint16_t*)attn_f32 + (size_t)b * NL * ROWU16;
  const uint16_t* Bt = qt + (size_t)b * ND * NL;
  int tid = threadIdx.x, lane = tid & 63, wave = tid >> 6;
  int wn = wave * 64;  // wave covers cols [wn, wn+64) of D=256
  int quad = lane >> 4, l15 = lane & 15;
  f32x4 acc[4][4] = {};

  if (tid < 64) {
    const float* pf = attn_f32 + (size_t)(b * NL + m0 + tid) * NL + 512;
    float s = pf[0] + pf[1] + pf[2] + pf[3] + pf[4] + pf[5] + pf[6] + pf[7];
    inv_lds[tid] = (s > 0.0f) ? 1.0f / s : 0.0f;
  }

  // expansion assignment: 256 threads cover 64 rows x 4 chunks-of-8-u16
  int xr = tid >> 2;  // local row 0..63
  int xc = tid & 3;   // which 8-u16 chunk within the 32-u16 K-step
  int xsw = (xr >> 1) & 3;
  float* xrow = attn_f32 + (size_t)(b * NL + m0 + xr) * NL;

  float4 p0, p1;
  float* pdst = nullptr;

  for (int k0 = NL - 32; k0 >= 0; k0 -= 32) {
    __syncthreads();
    // flush previous chunk's expansion (drains together with gld_lds below)
    if (k0 != NL - 32) {
      ((float4*)pdst)[0] = p0;
      ((float4*)pdst)[1] = p1;
    }
    {
      // A: 64 rows x 32 u16 = 4 KB, one gld_lds across 256 threads
      int row = tid >> 2, cc = tid & 3;
      int sw = (row >> 1) & 3;
      int gc = k0 + ((cc ^ sw) * 8);
      GLD_LDS16(Ap + (size_t)(m0 + row) * ROWU16 + gc,
                As + (size_t)(wave * 64) * 8);
    }
#pragma unroll
    for (int i = 0; i < 4; i++) {
      // B: 256 rows x 32 u16 = 16 KB, four gld_lds across 256 threads
      int c = i * 256 + tid;
      int row = c >> 2, cc = c & 3;
      int sw = (row >> 1) & 3;
      int gc = k0 + ((cc ^ sw) * 8);
      GLD_LDS16(Bt + (size_t)row * NL + gc,
                Bs + (size_t)(i * 256 + wave * 64) * 8);
    }
    __syncthreads();
    bf16x8 af[4], bfr[4];
#pragma unroll
    for (int t = 0; t < 4; t++) {
      int ra = t * 16 + l15;
      af[t] = *(const bf16x8*)(As + ra * 32 + ((quad ^ ((ra >> 1) & 3)) * 8));
      int rb = wn + t * 16 + l15;
      bfr[t] = *(const bf16x8*)(Bs + rb * 32 + ((quad ^ ((rb >> 1) & 3)) * 8));
    }
#pragma unroll
    for (int tm = 0; tm < 4; tm++)
#pragma unroll
      for (int tn = 0; tn < 4; tn++)
        acc[tm][tn] = __builtin_amdgcn_mfma_f32_16x16x32_bf16(
            af[tm], bfr[tn], acc[tm][tn], 0, 0, 0);

    // compute this chunk's expansion into registers (reads As; valid until
    // the next top-of-loop barrier). Store happens next iteration.
    {
      u16x8 hv = *(const u16x8*)(As + xr * 32 + ((xc ^ xsw) * 8));
      float inv = inv_lds[xr];
      p0.x = bf2f(hv[0]) * inv;
      p0.y = bf2f(hv[1]) * inv;
      p0.z = bf2f(hv[2]) * inv;
      p0.w = bf2f(hv[3]) * inv;
      p1.x = bf2f(hv[4]) * inv;
      p1.y = bf2f(hv[5]) * inv;
      p1.z = bf2f(hv[6]) * inv;
      p1.w = bf2f(hv[7]) * inv;
      pdst = xrow + k0 + xc * 8;
    }
  }
  // final flush (chunk k0 = 0)
  ((float4*)pdst)[0] = p0;
  ((float4*)pdst)[1] = p1;

  float* O = out + (size_t)b * NL * ND;
#pragma unroll
  for (int tm = 0; tm < 4; tm++) {
    int rbl = tm * 16 + quad * 4;
#pragma unroll
    for (int tn = 0; tn < 4; tn++) {
      int col = wn + tn * 16 + l15;
#pragma unroll
      for (int j = 0; j < 4; j++)
        O[(size_t)(m0 + rbl + j) * ND + col] = acc[tm][tn][j] * inv_lds[rbl + j];
    }
  }
}

// ---------------------------------------------------------------------------
extern "C" void kernel_launch(void* const* d_in, const int* in_sizes, int n_in,
                              void* d_out, int out_size, void* d_ws,
                              size_t ws_size, hipStream_t stream) {
  (void)in_sizes; (void)n_in; (void)out_size; (void)ws_size;
  const float* q = (const float*)d_in[0];
  float* out = (float*)d_out;
  float* attn = out + (size_t)NB * NL * ND;  // [output | attn] concat
  uint16_t* qb = (uint16_t*)d_ws;            // 16 MiB
  uint16_t* qt = qb + (size_t)NB * NL * ND;  // 16 MiB  (total = 32 MiB, as before)

  convert_kernel<<<dim3(16, 4, NB), 256, 0, stream>>>(q, qb, qt);
  qk_kernel<<<dim3(8, 8, NB), 256, 0, stream>>>(qb, attn);
  pv_kernel<<<dim3(16, 1, NB), 256, 0, stream>>>(attn, qt, out);
}

// Round 3
// 262.982 us; speedup vs baseline: 1.0162x; 1.0131x over previous
//
#include <hip/hip_runtime.h>
#include <stdint.h>

#define NB 32
#define NL 1024
#define ND 256

typedef __attribute__((ext_vector_type(8))) __bf16 bf16x8;
typedef __attribute__((ext_vector_type(4))) uint16_t u16x4;
typedef __attribute__((ext_vector_type(4))) float f32x4;

__device__ __forceinline__ uint16_t f2bf(float f) {
  union { float f; uint32_t u; } v; v.f = f;
  return (uint16_t)((v.u + 0x7fffu + ((v.u >> 16) & 1u)) >> 16);
}
__device__ __forceinline__ float bf2f(uint16_t h) {
  union { uint32_t u; float f; } v; v.u = ((uint32_t)h) << 16;
  return v.f;
}

#define GLD_LDS16(g, l)                                                        \
  __builtin_amdgcn_global_load_lds(                                            \
      (__attribute__((address_space(1))) void*)(g),                            \
      (__attribute__((address_space(3))) void*)(l), 16, 0, 0)

// ---------------------------------------------------------------------------
// Kernel 0: q fp32 -> Qb bf16 [b][l][d]  and  Qt bf16 [b][d][l]
// ---------------------------------------------------------------------------
__global__ __launch_bounds__(256) void convert_kernel(
    const float* __restrict__ q, uint16_t* __restrict__ qb,
    uint16_t* __restrict__ qt) {
  __shared__ uint16_t tile[64][72];
  int b = blockIdx.z;
  int l0 = blockIdx.x * 64, d0 = blockIdx.y * 64;
  int t = threadIdx.x;
  int r = t >> 4;
  int c4 = (t & 15) * 4;
  const float* qsrc = q + (size_t)b * NL * ND;
  uint16_t* qbb = qb + (size_t)b * NL * ND;
  uint16_t* qtb = qt + (size_t)b * ND * NL;
#pragma unroll
  for (int i = 0; i < 4; i++) {
    int row = r + 16 * i;
    float4 v = *(const float4*)(qsrc + (size_t)(l0 + row) * ND + d0 + c4);
    ushort4 h;
    h.x = f2bf(v.x); h.y = f2bf(v.y); h.z = f2bf(v.z); h.w = f2bf(v.w);
    *(ushort4*)(qbb + (size_t)(l0 + row) * ND + d0 + c4) = h;
    tile[row][c4 + 0] = h.x; tile[row][c4 + 1] = h.y;
    tile[row][c4 + 2] = h.z; tile[row][c4 + 3] = h.w;
  }
  __syncthreads();
#pragma unroll
  for (int i = 0; i < 4; i++) {
    int drow = r + 16 * i;
    ushort4 h;
    h.x = tile[c4 + 0][drow]; h.y = tile[c4 + 1][drow];
    h.z = tile[c4 + 2][drow]; h.w = tile[c4 + 3][drow];
    *(ushort4*)(qtb + (size_t)(d0 + drow) * NL + l0 + c4) = h;
  }
}

// ---------------------------------------------------------------------------
// Fused attention kernel: one block owns 64 m-rows end-to-end.
//   Phase 1 (QK): S = Qb Qb^T over n-steps of 128; P = exp(S/16) (S==0 -> 0)
//     written bf16 into LDS-resident P[64][1024] (granule-XOR swizzled),
//     rowsums accumulated in registers.
//   Phase 2 (PV): out = (P @ Q) * inv_rowsum from LDS P + staged qt chunks;
//     P is simultaneously expanded to normalized f32 attn (global), one
//     32-n chunk per PV iteration, overlapping the MFMAs.
// 512 threads = 8 waves: wave = (wmw: 4-way m-split of 16 rows) x
//                        (wnh: 2-way n-half for QK / d-half for PV).
// LDS: P 128 KB + pool 16 KB = 144 KB -> 1 block/CU, 2 waves/SIMD.
// ---------------------------------------------------------------------------
__global__ __launch_bounds__(512) void attn_kernel(
    const uint16_t* __restrict__ qb, const uint16_t* __restrict__ qt,
    float* __restrict__ attn, float* __restrict__ out) {
  __shared__ alignas(16) uint16_t P[64 * 1024];  // 128 KB, swizzled granules
  __shared__ alignas(16) uint16_t pool[8192];    // 16 KB: Bs dbuf / rowsums / Vs
  int b = blockIdx.z;
  int m0 = blockIdx.x * 64;
  const uint16_t* Q = qb + (size_t)b * NL * ND;
  const uint16_t* Bt = qt + (size_t)b * ND * NL;
  int tid = threadIdx.x, lane = tid & 63, wave = tid >> 6;
  int wmw = wave >> 1;   // 0..3 : m-rows [wmw*16, wmw*16+16)
  int wnh = wave & 1;    // 0..1 : n-half (QK) / d-half (PV)
  int quad = lane >> 4, l15 = lane & 15;
  int mw = wmw * 16 + l15;  // this lane's A-frag m-row (local 0..63)

  // ---- A-fragments, direct global -> registers (one-time, 32 KB/block) ----
  bf16x8 af[8];
#pragma unroll
  for (int kk = 0; kk < 8; kk++)
    af[kk] = *(const bf16x8*)(Q + (size_t)(m0 + mw) * ND + kk * 32 + quad * 8);

  // ---- QK phase. Bs double-buffered in pool (2 x 8 KB), 1 barrier/k-step ---
  {
    // prologue: stage (ns=0, k0=0) into buf 0
    int row = tid >> 2, cc = tid & 3;
    int sw = (row >> 1) & 3;
    GLD_LDS16(Q + (size_t)row * ND + ((cc ^ sw) * 8),
              pool + (size_t)(wave * 64) * 8);
  }
  float rsum[4] = {0.f, 0.f, 0.f, 0.f};
  const float kf = 0.09016844005555f;  // log2(e)/16
  int buf = 0;
  for (int ns = 0; ns < 8; ns++) {
    f32x4 sacc[4] = {};
    int n0 = ns * 128;
#pragma unroll
    for (int kk = 0; kk < 8; kk++) {
      __syncthreads();  // drains the in-flight stage for buf
      int step = ns * 8 + kk + 1;
      if (step < 64) {  // stage next k-chunk into the other buffer
        int nn0 = (step >> 3) * 128, kk0 = (step & 7) * 32;
        int row = tid >> 2, cc = tid & 3;
        int sw = (row >> 1) & 3;
        GLD_LDS16(Q + (size_t)(nn0 + row) * ND + kk0 + ((cc ^ sw) * 8),
                  pool + (size_t)((buf ^ 1) * 512 + wave * 64) * 8);
      }
      const uint16_t* Bb = pool + buf * 4096;
      bf16x8 bq[4];
#pragma unroll
      for (int t = 0; t < 4; t++) {
        int rb = wnh * 64 + t * 16 + l15;
        bq[t] = *(const bf16x8*)(Bb + rb * 32 + ((quad ^ ((rb >> 1) & 3)) * 8));
      }
#pragma unroll
      for (int t = 0; t < 4; t++)
        sacc[t] = __builtin_amdgcn_mfma_f32_16x16x32_bf16(af[kk], bq[t],
                                                          sacc[t], 0, 0, 0);
      buf ^= 1;
    }
    // epilogue for this n-step: exp -> P (LDS, swizzled) + rowsum partials
#pragma unroll
    for (int t = 0; t < 4; t++) {
      int n = n0 + wnh * 64 + t * 16 + l15;
      int g = n >> 3, e = n & 7;
#pragma unroll
      for (int j = 0; j < 4; j++) {
        int m = wmw * 16 + quad * 4 + j;
        float s = sacc[t][j];
        float ev = (s == 0.0f) ? 0.0f : __builtin_amdgcn_exp2f(s * kf);
        P[m * 1024 + (((g ^ (m & 7)) << 3) + e)] = f2bf(ev);
        rsum[j] += ev;
      }
    }
  }

  // ---- rowsum reduce -> pool (f32) -> registers ---------------------------
  __syncthreads();  // all Bs reads done; pool reusable. P writes fenced.
  float* poolf = (float*)pool;
#pragma unroll
  for (int j = 0; j < 4; j++) {
    float v = rsum[j];
    v += __shfl_xor(v, 1, 64);
    v += __shfl_xor(v, 2, 64);
    v += __shfl_xor(v, 4, 64);
    v += __shfl_xor(v, 8, 64);
    if (l15 == 0) poolf[(wmw * 16 + quad * 4 + j) * 2 + wnh] = v;
  }
  __syncthreads();
  float invo[4];
#pragma unroll
  for (int j = 0; j < 4; j++) {
    int r = wmw * 16 + quad * 4 + j;
    float s = poolf[r * 2] + poolf[r * 2 + 1];
    invo[j] = (s > 0.f) ? 1.f / s : 0.f;
  }
  int xm = tid >> 3, xs = tid & 7;  // expand assignment: row, 4-f32 slice
  float sx = poolf[xm * 2] + poolf[xm * 2 + 1];
  float invx = (sx > 0.f) ? 1.f / sx : 0.f;
  __syncthreads();  // inv reads done; pool now Vs

  // ---- PV phase + in-loop expansion ---------------------------------------
  f32x4 pacc[8] = {};
  {
    // prologue: stage Vs chunk 0 (qt[256 d][32 n] = 16 KB)
#pragma unroll
    for (int i = 0; i < 2; i++) {
      int c = i * 512 + tid;
      int row = c >> 2, cc = c & 3;
      int sw = (row >> 1) & 3;
      GLD_LDS16(Bt + (size_t)row * NL + ((cc ^ sw) * 8),
                pool + (size_t)(i * 512 + wave * 64) * 8);
    }
  }
  float* attnb = attn + ((size_t)b * NL + m0) * NL;
  for (int c = 0; c < 32; c++) {
    __syncthreads();  // drains stage of Vs chunk c (and expand stores c-1)
    // expand chunk c early: stores get a long window to retire
    int gx = c * 4 + (xs >> 1);
    u16x4 h =
        *(const u16x4*)(P + xm * 1024 + (((gx ^ (xm & 7)) << 3) + (xs & 1) * 4));
    float4 v4;
    v4.x = bf2f(h[0]) * invx; v4.y = bf2f(h[1]) * invx;
    v4.z = bf2f(h[2]) * invx; v4.w = bf2f(h[3]) * invx;
    *(float4*)(attnb + (size_t)xm * NL + c * 32 + xs * 4) = v4;
    // read MFMA operands for chunk c
    int gP = c * 4 + quad;
    bf16x8 pa = *(const bf16x8*)(P + mw * 1024 + ((gP ^ (mw & 7)) << 3));
    bf16x8 vb[8];
#pragma unroll
    for (int t = 0; t < 8; t++) {
      int rb = wnh * 128 + t * 16 + l15;
      vb[t] = *(const bf16x8*)(pool + rb * 32 + ((quad ^ ((rb >> 1) & 3)) * 8));
    }
    __syncthreads();  // all Vs reads complete (lgkm drained) -> safe to restage
    if (c < 31) {
      int n0c = (c + 1) * 32;
#pragma unroll
      for (int i = 0; i < 2; i++) {
        int cc2 = i * 512 + tid;
        int row = cc2 >> 2, ccc = cc2 & 3;
        int sw = (row >> 1) & 3;
        GLD_LDS16(Bt + (size_t)row * NL + n0c + ((ccc ^ sw) * 8),
                  pool + (size_t)(i * 512 + wave * 64) * 8);
      }
    }
#pragma unroll
    for (int t = 0; t < 8; t++)
      pacc[t] = __builtin_amdgcn_mfma_f32_16x16x32_bf16(pa, vb[t], pacc[t],
                                                        0, 0, 0);
  }

  // ---- out epilogue -------------------------------------------------------
  float* O = out + (size_t)b * NL * ND + (size_t)m0 * ND;
#pragma unroll
  for (int t = 0; t < 8; t++) {
    int col = wnh * 128 + t * 16 + l15;
#pragma unroll
    for (int j = 0; j < 4; j++) {
      int r = wmw * 16 + quad * 4 + j;
      O[(size_t)r * ND + col] = pacc[t][j] * invo[j];
    }
  }
}

// ---------------------------------------------------------------------------
extern "C" void kernel_launch(void* const* d_in, const int* in_sizes, int n_in,
                              void* d_out, int out_size, void* d_ws,
                              size_t ws_size, hipStream_t stream) {
  (void)in_sizes; (void)n_in; (void)out_size; (void)ws_size;
  const float* q = (const float*)d_in[0];
  float* out = (float*)d_out;
  float* attn = out + (size_t)NB * NL * ND;  // [output | attn] concat
  uint16_t* qb = (uint16_t*)d_ws;            // 16 MiB
  uint16_t* qt = qb + (size_t)NB * NL * ND;  // 16 MiB

  convert_kernel<<<dim3(16, 4, NB), 256, 0, stream>>>(q, qb, qt);
  attn_kernel<<<dim3(16, 1, NB), 512, 0, stream>>>(qb, qt, attn, out);
}